// Round 14
// baseline (49.641 us; speedup 1.0000x reference)
//
#include <hip/hip_runtime.h>
#include <math.h>

#define BATCH 8
#define CH    512
#define NPIX  1024
#define NH    4

typedef __attribute__((ext_vector_type(8))) short bf16x8;
typedef __attribute__((ext_vector_type(4))) float f32x4;
typedef __attribute__((ext_vector_type(16))) float f32x16;
typedef __attribute__((ext_vector_type(4))) int i32x4;
typedef __attribute__((ext_vector_type(4))) unsigned int u32x4;

// 1/sqrt(128) * log2(e): folded into Wq/bq so softmax = exp2(s - m)
#define QSC (0.088388347648318447f * 1.4426950408889634f)

// inline-asm loads: compiler cannot sink these; we manage vmcnt ourselves.
#define GLOAD0(dst, addr) asm volatile("global_load_dwordx4 %0, %1, off" \
    : "=v"(dst) : "v"(addr) : "memory")
#define GLOAD1(dst, addr) asm volatile("global_load_dwordx4 %0, %1, off offset:1024" \
    : "=v"(dst) : "v"(addr) : "memory")
#define WAITV12 asm volatile("s_waitcnt vmcnt(12)" ::: "memory")
#define WAITV6  asm volatile("s_waitcnt vmcnt(6)"  ::: "memory")
#define WAITV0  asm volatile("s_waitcnt vmcnt(0)"  ::: "memory")
#define SB      __builtin_amdgcn_sched_barrier(0)

__device__ inline unsigned short f2bf_rne(float f) {
    unsigned int u = __float_as_uint(f);
    return (unsigned short)((u + 0x7FFFu + ((u >> 16) & 1u)) >> 16);
}
__device__ inline unsigned int pack_bf2_trunc(float a, float b) {
    return (__float_as_uint(a) >> 16) | (__float_as_uint(b) & 0xFFFF0000u);
}
__device__ inline unsigned int pack2_rne(float a, float b) {
    return (unsigned int)f2bf_rne(a) | ((unsigned int)f2bf_rne(b) << 16);
}

// ---------------------------------------------------------------------------
// Prep (fused):
//  z<8  : X [b][c][n] fp32 -> XTF fragment-packed bf16 B-operand.
//  z==8 : W fp32 -> WF fragment-packed A-operand (Wq rows pre-scaled).
// ---------------------------------------------------------------------------
__global__ __launch_bounds__(256) void prep(
    const float* __restrict__ x,
    const float* __restrict__ Wq, const float* __restrict__ Wk,
    const float* __restrict__ Wv,
    unsigned short* __restrict__ XTF, unsigned short* __restrict__ WF)
{
    const int t = threadIdx.x;
    if (blockIdx.z == 8) {
        const int gid = blockIdx.y * 16 + blockIdx.x;   // 0..127
        #pragma unroll
        for (int rep = 0; rep < 2; ++rep) {
            const int idx = (rep * 128 + gid) * 256 + t;   // (o, k8) pairs
            if (idx < 49152) {
                const int o = idx >> 6, k8 = idx & 63;
                const float* src;
                float sc = 1.f;
                if (o < 128)      { src = Wq + (size_t)o * CH;        sc = QSC; }
                else if (o < 256) { src = Wk + (size_t)(o - 128) * CH; }
                else              { src = Wv + (size_t)(o - 256) * CH; }
                src += k8 * 8;
                const float4 v0 = *(const float4*)src;
                const float4 v1 = *(const float4*)(src + 4);
                u32x4 st;
                st.x = pack2_rne(v0.x * sc, v0.y * sc);
                st.y = pack2_rne(v0.z * sc, v0.w * sc);
                st.z = pack2_rne(v1.x * sc, v1.y * sc);
                st.w = pack2_rne(v1.z * sc, v1.w * sc);
                const int dst = (((o >> 4) * 16 + (k8 >> 2)) * 512
                              + (((o & 15) | ((k8 & 3) << 4))) * 8);
                *(u32x4*)&WF[dst] = st;
            }
        }
        return;
    }
    __shared__ float S[64][65];    // [k-local][n-local]
    const int a = t & 15, g = t >> 4;
    const int n0 = blockIdx.x * 64, c0 = blockIdx.y * 64, b = blockIdx.z;
    const float* xb = x + ((size_t)b * CH + c0) * NPIX + n0;
    #pragma unroll
    for (int i = 0; i < 4; ++i) {
        const int c = g + 16 * i;
        const float4 v = *(const float4*)&xb[(size_t)c * NPIX + 4 * a];
        S[c][4*a+0] = v.x; S[c][4*a+1] = v.y; S[c][4*a+2] = v.z; S[c][4*a+3] = v.w;
    }
    __syncthreads();
    const int n = t & 63;
    const int nt = (n0 >> 4) + (n >> 4);
    const int lo = n & 15;
    #pragma unroll
    for (int rep = 0; rep < 2; ++rep) {
        const int c8 = (t >> 6) + rep * 4;          // 0..7 (8 k's each)
        const int kkG = (c0 >> 5) + (c8 >> 2);
        const int hi = c8 & 3;
        u32x4 st;
        st.x = pack2_rne(S[c8*8+0][n], S[c8*8+1][n]);
        st.y = pack2_rne(S[c8*8+2][n], S[c8*8+3][n]);
        st.z = pack2_rne(S[c8*8+4][n], S[c8*8+5][n]);
        st.w = pack2_rne(S[c8*8+6][n], S[c8*8+7][n]);
        const size_t dst = (((size_t)b * 64 + nt) * 16 + kkG) * 512
                         + (size_t)((lo | (hi << 4))) * 8;
        *(u32x4*)&XTF[dst] = st;
    }
}

// ---------------------------------------------------------------------------
// QKV projection (unchanged, passing): fragment-packed operands, inline-asm
// double-buffered k-loop with counted vmcnt(6). Epilogues: Q/K via LDS
// swizzled transpose into frag-packed QF/KF; V sigma-packed into VF.
// ---------------------------------------------------------------------------
__global__ __launch_bounds__(256, 3) void qkv_proj(
    const unsigned short* __restrict__ XTF, const unsigned short* __restrict__ WF,
    const float* __restrict__ bq, const float* __restrict__ bk,
    const float* __restrict__ bv,
    unsigned short* __restrict__ QF, unsigned short* __restrict__ KF,
    unsigned short* __restrict__ VF)
{
    __shared__ unsigned short OT[4][2048];
    const int t = threadIdx.x, w = t >> 6, l = t & 63;
    const int lo = l & 15, hi = l >> 4;
    const int b = blockIdx.z;
    const int o0 = blockIdx.y * 64 + (w >> 1) * 32;
    const int n0 = blockIdx.x * 128 + (w & 1) * 64;

    const unsigned short* Ap0 = WF + (size_t)(o0 >> 4) * 8192 + l * 8;
    const unsigned short* Ap1 = Ap0 + 8192;
    const unsigned short* Bp0 = XTF + ((size_t)b * 64 + (n0 >> 4)) * 8192 + l * 8;
    const unsigned short* Bp1 = Bp0 + 8192;
    const unsigned short* Bp2 = Bp0 + 16384;
    const unsigned short* Bp3 = Bp0 + 24576;

    i32x4 ab[2][2], bb[2][4];
    GLOAD0(ab[0][0], Ap0); GLOAD0(ab[0][1], Ap1);
    GLOAD0(bb[0][0], Bp0); GLOAD0(bb[0][1], Bp1);
    GLOAD0(bb[0][2], Bp2); GLOAD0(bb[0][3], Bp3);
    Ap0 += 512; Ap1 += 512; Bp0 += 512; Bp1 += 512; Bp2 += 512; Bp3 += 512;
    GLOAD0(ab[1][0], Ap0); GLOAD0(ab[1][1], Ap1);
    GLOAD0(bb[1][0], Bp0); GLOAD0(bb[1][1], Bp1);
    GLOAD0(bb[1][2], Bp2); GLOAD0(bb[1][3], Bp3);
    Ap0 += 512; Ap1 += 512; Bp0 += 512; Bp1 += 512; Bp2 += 512; Bp3 += 512;

    f32x4 acc[2][4] = {};

    auto compute = [&](int cur) {
        bf16x8 af[2], bf[4];
        af[0] = __builtin_bit_cast(bf16x8, ab[cur][0]);
        af[1] = __builtin_bit_cast(bf16x8, ab[cur][1]);
        #pragma unroll
        for (int j = 0; j < 4; ++j) bf[j] = __builtin_bit_cast(bf16x8, bb[cur][j]);
        __builtin_amdgcn_s_setprio(1);
        #pragma unroll
        for (int i = 0; i < 2; ++i)
            #pragma unroll
            for (int j = 0; j < 4; ++j)
                acc[i][j] = __builtin_amdgcn_mfma_f32_16x16x32_bf16(af[i], bf[j], acc[i][j], 0, 0, 0);
        __builtin_amdgcn_s_setprio(0);
    };
    auto issue = [&](int cur) {
        GLOAD0(ab[cur][0], Ap0); GLOAD0(ab[cur][1], Ap1);
        GLOAD0(bb[cur][0], Bp0); GLOAD0(bb[cur][1], Bp1);
        GLOAD0(bb[cur][2], Bp2); GLOAD0(bb[cur][3], Bp3);
        Ap0 += 512; Ap1 += 512; Bp0 += 512; Bp1 += 512; Bp2 += 512; Bp3 += 512;
    };

    #pragma unroll 1
    for (int i = 0; i < 7; ++i) {
        WAITV6; SB;
        compute(0); issue(0);
        WAITV6; SB;
        compute(1); issue(1);
    }
    WAITV6; SB;
    compute(0);                       // k-step 14
    WAITV0; SB;
    compute(1);                       // k-step 15

    float bias[2][4];
    #pragma unroll
    for (int i = 0; i < 2; ++i)
        #pragma unroll
        for (int r = 0; r < 4; ++r) {
            const int orow = o0 + i * 16 + hi * 4 + r;
            if (o0 < 128)      bias[i][r] = bq[orow] * QSC;
            else if (o0 < 256) bias[i][r] = bk[orow - 128];
            else               bias[i][r] = bv[orow - 256];
        }

    if (o0 < 256) {
        const bool isQ = (o0 < 128);
        const int hh = (o0 & 127) >> 5;
        #pragma unroll
        for (int i = 0; i < 2; ++i)
            #pragma unroll
            for (int j = 0; j < 4; ++j) {
                const int nl = j * 16 + lo;
                const int og = i * 4 + hi;
                unsigned short v0 = f2bf_rne(acc[i][j][0] + bias[i][0]);
                unsigned short v1 = f2bf_rne(acc[i][j][1] + bias[i][1]);
                unsigned short v2 = f2bf_rne(acc[i][j][2] + bias[i][2]);
                unsigned short v3 = f2bf_rne(acc[i][j][3] + bias[i][3]);
                uint2 st;
                st.x = (unsigned int)v0 | ((unsigned int)v1 << 16);
                st.y = (unsigned int)v2 | ((unsigned int)v3 << 16);
                *(uint2*)&OT[w][nl * 32 + ((og ^ (nl & 7)) << 2)] = st;
            }
        unsigned short* outp = (isQ ? QF : KF) + (size_t)(b * NH + hh) * 32768;
        #pragma unroll
        for (int it = 0; it < 4; ++it) {
            const int nl = (l >> 2) + 16 * it, seg = l & 3;
            const int g0 = (2 * seg) ^ (nl & 7);
            const int g1 = (2 * seg + 1) ^ (nl & 7);
            const uint2 p0 = *(uint2*)&OT[w][nl * 32 + g0 * 4];
            const uint2 p1 = *(uint2*)&OT[w][nl * 32 + g1 * 4];
            uint4 st; st.x = p0.x; st.y = p0.y; st.z = p1.x; st.w = p1.y;
            const int nn = n0 + nl;
            const int dst = ((nn >> 5) << 10) | ((seg >> 1) << 9)
                          | ((((nn & 31) | ((seg & 1) << 5))) << 3);
            *(uint4*)&outp[dst] = st;
        }
    } else {
        const int hh  = (o0 - 256) >> 7;
        const int c64 = ((o0 - 256) >> 6) & 1;
        const int c32b= ((o0 - 256) >> 5) & 1;
        unsigned short* vfb = VF + (size_t)(b * NH + hh) * 131072
                                 + (size_t)c64 * 65536 + (size_t)c32b * 32768;
        #pragma unroll
        for (int i = 0; i < 2; ++i)
            #pragma unroll
            for (int j = 0; j < 4; ++j)
                #pragma unroll
                for (int r = 0; r < 4; ++r) {
                    const int c32 = i * 16 + hi * 4 + r;
                    const int n = n0 + j * 16 + lo;
                    const int np = (n & ~12) | ((n & 4) << 1) | ((n & 8) >> 1);
                    const int m5 = np & 31;
                    const int lidx = c32 | (((m5 >> 3) & 1) << 5);
                    const int idx = ((np >> 5) << 10) | ((m5 >> 4) << 9)
                                  | (lidx << 3) | (m5 & 7);
                    vfb[idx] = f2bf_rne(acc[i][j][r] + bias[i][r]);
                }
    }
}

// ---------------------------------------------------------------------------
// Fused flash attention v13 = v10 (proven) + 3-deep load pipeline (in-loop
// wait = vmcnt(12): two tiles of L2 latency hidden) + staggered tile order
// per wave (valid: online softmax is order-independent up to rounding).
// 64 q-rows per wave (groups A/B sharing K/V frags), register P, sigma-packed
// V, defer-max, kv-merge through LDS.
// ---------------------------------------------------------------------------
__global__ __launch_bounds__(256, 2) void attn(
    const unsigned short* __restrict__ QF, const unsigned short* __restrict__ KF,
    const unsigned short* __restrict__ VF, const float* __restrict__ x,
    const float* __restrict__ gamma, float* __restrict__ out)
{
    __shared__ float Xof[8192];            // donor partials
    __shared__ float mlM[128], mlL[128];   // donor max / sum

    const int t = threadIdx.x, w = t >> 6, l = t & 63;
    const int xl = l & 31;
    const int h  = l >> 5;
    const int kv = w & 1, ch = w >> 1;

    // XCD-grouped decode: u%8 = bh%8 -> per-XCD working set L2-resident
    const int u = blockIdx.x;              // 0..511
    const int xcd = u & 7;
    const int rr = u >> 3;                 // 0..63
    const int nt = rr & 15;                // 16 n-tiles of 64 rows
    const int bh = xcd | ((rr >> 4) << 3); // 0..31
    const int n0 = nt * 64;

    const unsigned short* Kb0 = KF + (((size_t)bh * 32 + kv * 16) << 10) + l * 8;
    const unsigned short* Vb0 = VF + (size_t)bh * 131072 + (size_t)ch * 65536
                                   + (((size_t)kv * 16) << 10) + l * 8;
    const unsigned short* Vb1 = Vb0 + 32768;
    const unsigned short* Qa  = QF + (((size_t)bh * 32 + nt * 2) << 10) + l * 8;

    // staggered tile order (order only changes rounding for online softmax)
    const int start = (rr * 3 + w * 4) & 15;
    auto toff = [&](int i) { return (size_t)(((start + i) & 15) << 10); };

    i32x4 qr0, qr1, qr2, qr3;
    GLOAD0(qr0, Qa); GLOAD1(qr1, Qa);                 // group A rows
    GLOAD0(qr2, Qa + 1024); GLOAD1(qr3, Qa + 1024);   // group B rows

    i32x4 kb[3][2], v0b[3][2], v1b[3][2];

    auto issue = [&](int cur, int i) {
        const unsigned short* kp  = Kb0 + toff(i);
        const unsigned short* vp0 = Vb0 + toff(i);
        const unsigned short* vp1 = Vb1 + toff(i);
        GLOAD0(kb[cur][0], kp);   GLOAD1(kb[cur][1], kp);
        GLOAD0(v0b[cur][0], vp0); GLOAD1(v0b[cur][1], vp0);
        GLOAD0(v1b[cur][0], vp1); GLOAD1(v1b[cur][1], vp1);
    };

    issue(0, 0); issue(1, 1); issue(2, 2);   // 18 tile loads + 4 Q = 22 in flight

    f32x16 ofA0 = {}, ofA1 = {}, ofB0 = {}, ofB1 = {};
    float mrowA = -INFINITY, lrowA = 0.f;
    float mrowB = -INFINITY, lrowB = 0.f;

    auto compute = [&](int cur) {
        const bf16x8 ck0 = __builtin_bit_cast(bf16x8, kb[cur][0]);
        const bf16x8 ck1 = __builtin_bit_cast(bf16x8, kb[cur][1]);
        const bf16x8 cv0 = __builtin_bit_cast(bf16x8, v0b[cur][0]);
        const bf16x8 cv1 = __builtin_bit_cast(bf16x8, v0b[cur][1]);
        const bf16x8 cv2 = __builtin_bit_cast(bf16x8, v1b[cur][0]);
        const bf16x8 cv3 = __builtin_bit_cast(bf16x8, v1b[cur][1]);
        const bf16x8 qA0 = __builtin_bit_cast(bf16x8, qr0);
        const bf16x8 qA1 = __builtin_bit_cast(bf16x8, qr1);
        const bf16x8 qB0 = __builtin_bit_cast(bf16x8, qr2);
        const bf16x8 qB1 = __builtin_bit_cast(bf16x8, qr3);

        const f32x16 z16 = {};
        __builtin_amdgcn_s_setprio(1);
        f32x16 sa = __builtin_amdgcn_mfma_f32_32x32x16_bf16(ck0, qA0, z16, 0, 0, 0);
        f32x16 sb = __builtin_amdgcn_mfma_f32_32x32x16_bf16(ck0, qB0, z16, 0, 0, 0);
        sa = __builtin_amdgcn_mfma_f32_32x32x16_bf16(ck1, qA1, sa, 0, 0, 0);
        sb = __builtin_amdgcn_mfma_f32_32x32x16_bf16(ck1, qB1, sb, 0, 0, 0);
        __builtin_amdgcn_s_setprio(0);

        float a0 = fmaxf(fmaxf(sa[0], sa[1]), fmaxf(sa[2], sa[3]));
        float a1 = fmaxf(fmaxf(sa[4], sa[5]), fmaxf(sa[6], sa[7]));
        float a2 = fmaxf(fmaxf(sa[8], sa[9]), fmaxf(sa[10], sa[11]));
        float a3 = fmaxf(fmaxf(sa[12], sa[13]), fmaxf(sa[14], sa[15]));
        float mxA = fmaxf(fmaxf(a0, a1), fmaxf(a2, a3));
        float b0 = fmaxf(fmaxf(sb[0], sb[1]), fmaxf(sb[2], sb[3]));
        float b1 = fmaxf(fmaxf(sb[4], sb[5]), fmaxf(sb[6], sb[7]));
        float b2 = fmaxf(fmaxf(sb[8], sb[9]), fmaxf(sb[10], sb[11]));
        float b3 = fmaxf(fmaxf(sb[12], sb[13]), fmaxf(sb[14], sb[15]));
        float mxB = fmaxf(fmaxf(b0, b1), fmaxf(b2, b3));
        mxA = fmaxf(mxA, __shfl_xor(mxA, 32));
        mxB = fmaxf(mxB, __shfl_xor(mxB, 32));

        if (__any(mxA > mrowA + 11.5f)) {
            const float mnew = fmaxf(mrowA, mxA);
            const float fsc = __builtin_amdgcn_exp2f(mrowA - mnew);
            mrowA = mnew; lrowA *= fsc;
            ofA0 *= fsc; ofA1 *= fsc;
        }
        if (__any(mxB > mrowB + 11.5f)) {
            const float mnew = fmaxf(mrowB, mxB);
            const float fsc = __builtin_amdgcn_exp2f(mrowB - mnew);
            mrowB = mnew; lrowB *= fsc;
            ofB0 *= fsc; ofB1 *= fsc;
        }

        float pA[16], pB[16];
        #pragma unroll
        for (int r = 0; r < 16; ++r) pA[r] = __builtin_amdgcn_exp2f(sa[r] - mrowA);
        #pragma unroll
        for (int r = 0; r < 16; ++r) pB[r] = __builtin_amdgcn_exp2f(sb[r] - mrowB);
        lrowA += (((pA[0]+pA[1])+(pA[2]+pA[3])) + ((pA[4]+pA[5])+(pA[6]+pA[7])))
               + (((pA[8]+pA[9])+(pA[10]+pA[11])) + ((pA[12]+pA[13])+(pA[14]+pA[15])));
        lrowB += (((pB[0]+pB[1])+(pB[2]+pB[3])) + ((pB[4]+pB[5])+(pB[6]+pB[7])))
               + (((pB[8]+pB[9])+(pB[10]+pB[11])) + ((pB[12]+pB[13])+(pB[14]+pB[15])));

        u32x4 wA0, wA1, wB0, wB1;
        wA0.x = pack_bf2_trunc(pA[0],  pA[1]);  wA0.y = pack_bf2_trunc(pA[2],  pA[3]);
        wA0.z = pack_bf2_trunc(pA[4],  pA[5]);  wA0.w = pack_bf2_trunc(pA[6],  pA[7]);
        wA1.x = pack_bf2_trunc(pA[8],  pA[9]);  wA1.y = pack_bf2_trunc(pA[10], pA[11]);
        wA1.z = pack_bf2_trunc(pA[12], pA[13]); wA1.w = pack_bf2_trunc(pA[14], pA[15]);
        wB0.x = pack_bf2_trunc(pB[0],  pB[1]);  wB0.y = pack_bf2_trunc(pB[2],  pB[3]);
        wB0.z = pack_bf2_trunc(pB[4],  pB[5]);  wB0.w = pack_bf2_trunc(pB[6],  pB[7]);
        wB1.x = pack_bf2_trunc(pB[8],  pB[9]);  wB1.y = pack_bf2_trunc(pB[10], pB[11]);
        wB1.z = pack_bf2_trunc(pB[12], pB[13]); wB1.w = pack_bf2_trunc(pB[14], pB[15]);
        const bf16x8 pfA0 = __builtin_bit_cast(bf16x8, wA0);
        const bf16x8 pfA1 = __builtin_bit_cast(bf16x8, wA1);
        const bf16x8 pfB0 = __builtin_bit_cast(bf16x8, wB0);
        const bf16x8 pfB1 = __builtin_bit_cast(bf16x8, wB1);

        __builtin_amdgcn_s_setprio(1);
        ofA0 = __builtin_amdgcn_mfma_f32_32x32x16_bf16(cv0, pfA0, ofA0, 0, 0, 0);
        ofB0 = __builtin_amdgcn_mfma_f32_32x32x16_bf16(cv0, pfB0, ofB0, 0, 0, 0);
        ofA0 = __builtin_amdgcn_mfma_f32_32x32x16_bf16(cv1, pfA1, ofA0, 0, 0, 0);
        ofB0 = __builtin_amdgcn_mfma_f32_32x32x16_bf16(cv1, pfB1, ofB0, 0, 0, 0);
        ofA1 = __builtin_amdgcn_mfma_f32_32x32x16_bf16(cv2, pfA0, ofA1, 0, 0, 0);
        ofB1 = __builtin_amdgcn_mfma_f32_32x32x16_bf16(cv2, pfB0, ofB1, 0, 0, 0);
        ofA1 = __builtin_amdgcn_mfma_f32_32x32x16_bf16(cv3, pfA1, ofA1, 0, 0, 0);
        ofB1 = __builtin_amdgcn_mfma_f32_32x32x16_bf16(cv3, pfB1, ofB1, 0, 0, 0);
        __builtin_amdgcn_s_setprio(0);
    };

    // 3-deep pipeline: computes t0..t15, issues t3..t15; in-loop wait=vmcnt(12)
    #pragma unroll 1
    for (int j = 0; j < 4; ++j) {
        WAITV12; SB; compute(0); issue(0, 3 * j + 3);
        WAITV12; SB; compute(1); issue(1, 3 * j + 4);
        WAITV12; SB; compute(2); issue(2, 3 * j + 5);
    }
    WAITV12; SB; compute(0); issue(0, 15);   // t12; issue t15 into buf 0
    WAITV12; SB; compute(1);                 // t13
    WAITV6;  SB; compute(2);                 // t14
    WAITV0;  SB; compute(0);                 // t15

    // ---- merge kv partials ----
    lrowA += __shfl_xor(lrowA, 32);
    lrowB += __shfl_xor(lrowB, 32);
    if (kv == 1) {
        #pragma unroll
        for (int r = 0; r < 16; ++r) {
            Xof[((ch * 2 + 0) * 16 + r) * 64 + l]        = ofA0[r];
            Xof[((ch * 2 + 1) * 16 + r) * 64 + l]        = ofA1[r];
            Xof[4096 + ((ch * 2 + 0) * 16 + r) * 64 + l] = ofB0[r];
            Xof[4096 + ((ch * 2 + 1) * 16 + r) * 64 + l] = ofB1[r];
        }
        if (h == 0) {
            mlM[ch * 32 + xl] = mrowA;      mlL[ch * 32 + xl] = lrowA;
            mlM[64 + ch * 32 + xl] = mrowB; mlL[64 + ch * 32 + xl] = lrowB;
        }
    }
    __syncthreads();

    if (kv == 0) {
        const float g = gamma[0];
        const int b = bh >> 2, hd = bh & 3;
        const size_t base = ((size_t)b * CH + hd * 128 + ch * 64) * NPIX + n0;
        // group A
        {
            const float mB_ = mlM[ch * 32 + xl], lB_ = mlL[ch * 32 + xl];
            const float ms = fmaxf(mrowA, mB_);
            const float fA = __builtin_amdgcn_exp2f(mrowA - ms);
            const float fB = __builtin_amdgcn_exp2f(mB_ - ms);
            const float inv = 1.0f / (lrowA * fA + lB_ * fB);
            const float sA = fA * inv, sB = fB * inv;
            #pragma unroll
            for (int cb = 0; cb < 2; ++cb)
                #pragma unroll
                for (int r = 0; r < 16; ++r) {
                    const float own = cb ? ofA1[r] : ofA0[r];
                    const float dn  = Xof[((ch * 2 + cb) * 16 + r) * 64 + l];
                    const int   c   = cb * 32 + (r & 3) + 8 * (r >> 2) + 4 * h;
                    const size_t gi = base + (size_t)c * NPIX + xl;
                    out[gi] = fmaf(g, own * sA + dn * sB, x[gi]);
                }
        }
        // group B (rows n0+32..n0+63)
        {
            const float mB_ = mlM[64 + ch * 32 + xl], lB_ = mlL[64 + ch * 32 + xl];
            const float ms = fmaxf(mrowB, mB_);
            const float fA = __builtin_amdgcn_exp2f(mrowB - ms);
            const float fB = __builtin_amdgcn_exp2f(mB_ - ms);
            const float inv = 1.0f / (lrowB * fA + lB_ * fB);
            const float sA = fA * inv, sB = fB * inv;
            #pragma unroll
            for (int cb = 0; cb < 2; ++cb)
                #pragma unroll
                for (int r = 0; r < 16; ++r) {
                    const float own = cb ? ofB1[r] : ofB0[r];
                    const float dn  = Xof[4096 + ((ch * 2 + cb) * 16 + r) * 64 + l];
                    const int   c   = cb * 32 + (r & 3) + 8 * (r >> 2) + 4 * h;
                    const size_t gi = base + (size_t)c * NPIX + 32 + xl;
                    out[gi] = fmaf(g, own * sA + dn * sB, x[gi]);
                }
        }
    }
}

// ---------------------------------------------------------------------------
extern "C" void kernel_launch(void* const* d_in, const int* in_sizes, int n_in,
                              void* d_out, int out_size, void* d_ws, size_t ws_size,
                              hipStream_t stream)
{
    const float* x     = (const float*)d_in[0];
    const float* Wq    = (const float*)d_in[1];
    const float* bq    = (const float*)d_in[2];
    const float* Wk    = (const float*)d_in[3];
    const float* bk    = (const float*)d_in[4];
    const float* Wv    = (const float*)d_in[5];
    const float* bv    = (const float*)d_in[6];
    const float* gamma = (const float*)d_in[7];
    float* out = (float*)d_out;

    char* ws = (char*)d_ws;
    unsigned short* XTFp = (unsigned short*)(ws);             // 8 MB
    unsigned short* WFp  = (unsigned short*)(ws + 8388608);   // 768 KB
    unsigned short* QFp  = (unsigned short*)(ws + 9175040);   // 2 MB
    unsigned short* KFp  = (unsigned short*)(ws + 11272192);  // 2 MB
    unsigned short* VFp  = (unsigned short*)(ws + 13369344);  // 8 MB

    prep<<<dim3(16, 8, 9), 256, 0, stream>>>(x, Wq, Wk, Wv, XTFp, WFp);
    qkv_proj<<<dim3(8, 12, 8), 256, 0, stream>>>(XTFp, WFp, bq, bk, bv, QFp, KFp, VFp);
    attn<<<dim3(512), 256, 0, stream>>>(QFp, KFp, VFp, x, gamma, out);
}

// Round 15
// 47.584 us; speedup vs baseline: 1.0432x; 1.0432x over previous
//
#include <hip/hip_runtime.h>
#include <math.h>

#define BATCH 8
#define CH    512
#define NPIX  1024
#define NH    4

typedef __attribute__((ext_vector_type(8))) short bf16x8;
typedef __attribute__((ext_vector_type(4))) float f32x4;
typedef __attribute__((ext_vector_type(16))) float f32x16;
typedef __attribute__((ext_vector_type(4))) int i32x4;
typedef __attribute__((ext_vector_type(4))) unsigned int u32x4;

// 1/sqrt(128) * log2(e): folded into Wq/bq so softmax = exp2(s - m)
#define QSC (0.088388347648318447f * 1.4426950408889634f)

// inline-asm loads: compiler cannot sink these; we manage vmcnt ourselves.
#define GLOAD0(dst, addr) asm volatile("global_load_dwordx4 %0, %1, off" \
    : "=v"(dst) : "v"(addr) : "memory")
#define GLOAD1(dst, addr) asm volatile("global_load_dwordx4 %0, %1, off offset:1024" \
    : "=v"(dst) : "v"(addr) : "memory")
#define WAITV6  asm volatile("s_waitcnt vmcnt(6)"  ::: "memory")
#define WAITV0  asm volatile("s_waitcnt vmcnt(0)"  ::: "memory")
#define SB      __builtin_amdgcn_sched_barrier(0)

__device__ inline unsigned short f2bf_rne(float f) {
    unsigned int u = __float_as_uint(f);
    return (unsigned short)((u + 0x7FFFu + ((u >> 16) & 1u)) >> 16);
}
__device__ inline unsigned int pack_bf2_trunc(float a, float b) {
    return (__float_as_uint(a) >> 16) | (__float_as_uint(b) & 0xFFFF0000u);
}
__device__ inline unsigned int pack2_rne(float a, float b) {
    return (unsigned int)f2bf_rne(a) | ((unsigned int)f2bf_rne(b) << 16);
}
// cross-half (lane i <-> i^32) max at VALU rate: A,B=x -> A={r0,r0}, B={r1,r1}
__device__ inline float xhalf_max(float x) {
    float a = x, b = x;
    asm("v_permlane32_swap_b32 %0, %1" : "+v"(a), "+v"(b));
    return fmaxf(a, b);
}

// ---------------------------------------------------------------------------
// Prep (fused):
//  z<8  : X [b][c][n] fp32 -> XTF fragment-packed bf16 B-operand.
//  z==8 : W fp32 -> WF fragment-packed A-operand (Wq rows pre-scaled).
// ---------------------------------------------------------------------------
__global__ __launch_bounds__(256) void prep(
    const float* __restrict__ x,
    const float* __restrict__ Wq, const float* __restrict__ Wk,
    const float* __restrict__ Wv,
    unsigned short* __restrict__ XTF, unsigned short* __restrict__ WF)
{
    const int t = threadIdx.x;
    if (blockIdx.z == 8) {
        const int gid = blockIdx.y * 16 + blockIdx.x;   // 0..127
        #pragma unroll
        for (int rep = 0; rep < 2; ++rep) {
            const int idx = (rep * 128 + gid) * 256 + t;   // (o, k8) pairs
            if (idx < 49152) {
                const int o = idx >> 6, k8 = idx & 63;
                const float* src;
                float sc = 1.f;
                if (o < 128)      { src = Wq + (size_t)o * CH;        sc = QSC; }
                else if (o < 256) { src = Wk + (size_t)(o - 128) * CH; }
                else              { src = Wv + (size_t)(o - 256) * CH; }
                src += k8 * 8;
                const float4 v0 = *(const float4*)src;
                const float4 v1 = *(const float4*)(src + 4);
                u32x4 st;
                st.x = pack2_rne(v0.x * sc, v0.y * sc);
                st.y = pack2_rne(v0.z * sc, v0.w * sc);
                st.z = pack2_rne(v1.x * sc, v1.y * sc);
                st.w = pack2_rne(v1.z * sc, v1.w * sc);
                const int dst = (((o >> 4) * 16 + (k8 >> 2)) * 512
                              + (((o & 15) | ((k8 & 3) << 4))) * 8);
                *(u32x4*)&WF[dst] = st;
            }
        }
        return;
    }
    __shared__ float S[64][65];    // [k-local][n-local]
    const int a = t & 15, g = t >> 4;
    const int n0 = blockIdx.x * 64, c0 = blockIdx.y * 64, b = blockIdx.z;
    const float* xb = x + ((size_t)b * CH + c0) * NPIX + n0;
    #pragma unroll
    for (int i = 0; i < 4; ++i) {
        const int c = g + 16 * i;
        const float4 v = *(const float4*)&xb[(size_t)c * NPIX + 4 * a];
        S[c][4*a+0] = v.x; S[c][4*a+1] = v.y; S[c][4*a+2] = v.z; S[c][4*a+3] = v.w;
    }
    __syncthreads();
    const int n = t & 63;
    const int nt = (n0 >> 4) + (n >> 4);
    const int lo = n & 15;
    #pragma unroll
    for (int rep = 0; rep < 2; ++rep) {
        const int c8 = (t >> 6) + rep * 4;          // 0..7 (8 k's each)
        const int kkG = (c0 >> 5) + (c8 >> 2);
        const int hi = c8 & 3;
        u32x4 st;
        st.x = pack2_rne(S[c8*8+0][n], S[c8*8+1][n]);
        st.y = pack2_rne(S[c8*8+2][n], S[c8*8+3][n]);
        st.z = pack2_rne(S[c8*8+4][n], S[c8*8+5][n]);
        st.w = pack2_rne(S[c8*8+6][n], S[c8*8+7][n]);
        const size_t dst = (((size_t)b * 64 + nt) * 16 + kkG) * 512
                         + (size_t)((lo | (hi << 4))) * 8;
        *(u32x4*)&XTF[dst] = st;
    }
}

// ---------------------------------------------------------------------------
// QKV projection: fragment-packed operands, inline-asm double-buffered k-loop
// with counted vmcnt(6). No setprio (hurts lockstep structures, m190).
// Epilogues: Q/K via LDS swizzled transpose into frag-packed QF/KF; V
// sigma-packed into VF.
// ---------------------------------------------------------------------------
__global__ __launch_bounds__(256, 3) void qkv_proj(
    const unsigned short* __restrict__ XTF, const unsigned short* __restrict__ WF,
    const float* __restrict__ bq, const float* __restrict__ bk,
    const float* __restrict__ bv,
    unsigned short* __restrict__ QF, unsigned short* __restrict__ KF,
    unsigned short* __restrict__ VF)
{
    __shared__ unsigned short OT[4][2048];
    const int t = threadIdx.x, w = t >> 6, l = t & 63;
    const int lo = l & 15, hi = l >> 4;
    const int b = blockIdx.z;
    const int o0 = blockIdx.y * 64 + (w >> 1) * 32;
    const int n0 = blockIdx.x * 128 + (w & 1) * 64;

    const unsigned short* Ap0 = WF + (size_t)(o0 >> 4) * 8192 + l * 8;
    const unsigned short* Ap1 = Ap0 + 8192;
    const unsigned short* Bp0 = XTF + ((size_t)b * 64 + (n0 >> 4)) * 8192 + l * 8;
    const unsigned short* Bp1 = Bp0 + 8192;
    const unsigned short* Bp2 = Bp0 + 16384;
    const unsigned short* Bp3 = Bp0 + 24576;

    i32x4 ab[2][2], bb[2][4];
    GLOAD0(ab[0][0], Ap0); GLOAD0(ab[0][1], Ap1);
    GLOAD0(bb[0][0], Bp0); GLOAD0(bb[0][1], Bp1);
    GLOAD0(bb[0][2], Bp2); GLOAD0(bb[0][3], Bp3);
    Ap0 += 512; Ap1 += 512; Bp0 += 512; Bp1 += 512; Bp2 += 512; Bp3 += 512;
    GLOAD0(ab[1][0], Ap0); GLOAD0(ab[1][1], Ap1);
    GLOAD0(bb[1][0], Bp0); GLOAD0(bb[1][1], Bp1);
    GLOAD0(bb[1][2], Bp2); GLOAD0(bb[1][3], Bp3);
    Ap0 += 512; Ap1 += 512; Bp0 += 512; Bp1 += 512; Bp2 += 512; Bp3 += 512;

    f32x4 acc[2][4] = {};

    auto compute = [&](int cur) {
        bf16x8 af[2], bf[4];
        af[0] = __builtin_bit_cast(bf16x8, ab[cur][0]);
        af[1] = __builtin_bit_cast(bf16x8, ab[cur][1]);
        #pragma unroll
        for (int j = 0; j < 4; ++j) bf[j] = __builtin_bit_cast(bf16x8, bb[cur][j]);
        #pragma unroll
        for (int i = 0; i < 2; ++i)
            #pragma unroll
            for (int j = 0; j < 4; ++j)
                acc[i][j] = __builtin_amdgcn_mfma_f32_16x16x32_bf16(af[i], bf[j], acc[i][j], 0, 0, 0);
    };
    auto issue = [&](int cur) {
        GLOAD0(ab[cur][0], Ap0); GLOAD0(ab[cur][1], Ap1);
        GLOAD0(bb[cur][0], Bp0); GLOAD0(bb[cur][1], Bp1);
        GLOAD0(bb[cur][2], Bp2); GLOAD0(bb[cur][3], Bp3);
        Ap0 += 512; Ap1 += 512; Bp0 += 512; Bp1 += 512; Bp2 += 512; Bp3 += 512;
    };

    #pragma unroll 1
    for (int i = 0; i < 7; ++i) {
        WAITV6; SB;
        compute(0); issue(0);
        WAITV6; SB;
        compute(1); issue(1);
    }
    WAITV6; SB;
    compute(0);                       // k-step 14
    WAITV0; SB;
    compute(1);                       // k-step 15

    float bias[2][4];
    #pragma unroll
    for (int i = 0; i < 2; ++i)
        #pragma unroll
        for (int r = 0; r < 4; ++r) {
            const int orow = o0 + i * 16 + hi * 4 + r;
            if (o0 < 128)      bias[i][r] = bq[orow] * QSC;
            else if (o0 < 256) bias[i][r] = bk[orow - 128];
            else               bias[i][r] = bv[orow - 256];
        }

    if (o0 < 256) {
        const bool isQ = (o0 < 128);
        const int hh = (o0 & 127) >> 5;
        #pragma unroll
        for (int i = 0; i < 2; ++i)
            #pragma unroll
            for (int j = 0; j < 4; ++j) {
                const int nl = j * 16 + lo;
                const int og = i * 4 + hi;
                unsigned short v0 = f2bf_rne(acc[i][j][0] + bias[i][0]);
                unsigned short v1 = f2bf_rne(acc[i][j][1] + bias[i][1]);
                unsigned short v2 = f2bf_rne(acc[i][j][2] + bias[i][2]);
                unsigned short v3 = f2bf_rne(acc[i][j][3] + bias[i][3]);
                uint2 st;
                st.x = (unsigned int)v0 | ((unsigned int)v1 << 16);
                st.y = (unsigned int)v2 | ((unsigned int)v3 << 16);
                *(uint2*)&OT[w][nl * 32 + ((og ^ (nl & 7)) << 2)] = st;
            }
        unsigned short* outp = (isQ ? QF : KF) + (size_t)(b * NH + hh) * 32768;
        #pragma unroll
        for (int it = 0; it < 4; ++it) {
            const int nl = (l >> 2) + 16 * it, seg = l & 3;
            const int g0 = (2 * seg) ^ (nl & 7);
            const int g1 = (2 * seg + 1) ^ (nl & 7);
            const uint2 p0 = *(uint2*)&OT[w][nl * 32 + g0 * 4];
            const uint2 p1 = *(uint2*)&OT[w][nl * 32 + g1 * 4];
            uint4 st; st.x = p0.x; st.y = p0.y; st.z = p1.x; st.w = p1.y;
            const int nn = n0 + nl;
            const int dst = ((nn >> 5) << 10) | ((seg >> 1) << 9)
                          | ((((nn & 31) | ((seg & 1) << 5))) << 3);
            *(uint4*)&outp[dst] = st;
        }
    } else {
        const int hh  = (o0 - 256) >> 7;
        const int c64 = ((o0 - 256) >> 6) & 1;
        const int c32b= ((o0 - 256) >> 5) & 1;
        unsigned short* vfb = VF + (size_t)(b * NH + hh) * 131072
                                 + (size_t)c64 * 65536 + (size_t)c32b * 32768;
        #pragma unroll
        for (int i = 0; i < 2; ++i)
            #pragma unroll
            for (int j = 0; j < 4; ++j)
                #pragma unroll
                for (int r = 0; r < 4; ++r) {
                    const int c32 = i * 16 + hi * 4 + r;
                    const int n = n0 + j * 16 + lo;
                    const int np = (n & ~12) | ((n & 4) << 1) | ((n & 8) >> 1);
                    const int m5 = np & 31;
                    const int lidx = c32 | (((m5 >> 3) & 1) << 5);
                    const int idx = ((np >> 5) << 10) | ((m5 >> 4) << 9)
                                  | (lidx << 3) | (m5 & 7);
                    vfb[idx] = f2bf_rne(acc[i][j][r] + bias[i][r]);
                }
    }
}

// ---------------------------------------------------------------------------
// Fused flash attention v14 = v10/v11 (proven 48.0) with:
//  - all s_setprio removed (measured negative on lockstep structures)
//  - in-loop cross-half max via v_permlane32_swap_b32 (VALU rate) instead of
//    ds_bpermute shfl (~120cy LDS round-trip on the softmax critical path)
// 64 q-rows per wave (groups A/B sharing K/V frags), register P, sigma-packed
// V, defer-max, 2-deep asm pipeline vmcnt(6), kv-merge through LDS.
// ---------------------------------------------------------------------------
__global__ __launch_bounds__(256, 2) void attn(
    const unsigned short* __restrict__ QF, const unsigned short* __restrict__ KF,
    const unsigned short* __restrict__ VF, const float* __restrict__ x,
    const float* __restrict__ gamma, float* __restrict__ out)
{
    __shared__ float Xof[8192];            // donor partials
    __shared__ float mlM[128], mlL[128];   // donor max / sum

    const int t = threadIdx.x, w = t >> 6, l = t & 63;
    const int xl = l & 31;
    const int h  = l >> 5;
    const int kv = w & 1, ch = w >> 1;

    // XCD-grouped decode: u%8 = bh%8 -> per-XCD working set L2-resident
    const int u = blockIdx.x;              // 0..511
    const int xcd = u & 7;
    const int rr = u >> 3;                 // 0..63
    const int nt = rr & 15;                // 16 n-tiles of 64 rows
    const int bh = xcd | ((rr >> 4) << 3); // 0..31
    const int n0 = nt * 64;

    const unsigned short* Kp  = KF + (((size_t)bh * 32 + kv * 16) << 10) + l * 8;
    const unsigned short* Vp0 = VF + (size_t)bh * 131072 + (size_t)ch * 65536
                                   + (((size_t)kv * 16) << 10) + l * 8;
    const unsigned short* Vp1 = Vp0 + 32768;
    const unsigned short* Qa  = QF + (((size_t)bh * 32 + nt * 2) << 10) + l * 8;

    i32x4 qr0, qr1, qr2, qr3;
    GLOAD0(qr0, Qa); GLOAD1(qr1, Qa);                 // group A rows
    GLOAD0(qr2, Qa + 1024); GLOAD1(qr3, Qa + 1024);   // group B rows

    i32x4 kb[2][2], v0b[2][2], v1b[2][2];
    // prologue: tiles 0 and 1
    GLOAD0(kb[0][0], Kp);  GLOAD1(kb[0][1], Kp);
    GLOAD0(v0b[0][0], Vp0); GLOAD1(v0b[0][1], Vp0);
    GLOAD0(v1b[0][0], Vp1); GLOAD1(v1b[0][1], Vp1);
    Kp += 1024; Vp0 += 1024; Vp1 += 1024;
    GLOAD0(kb[1][0], Kp);  GLOAD1(kb[1][1], Kp);
    GLOAD0(v0b[1][0], Vp0); GLOAD1(v0b[1][1], Vp0);
    GLOAD0(v1b[1][0], Vp1); GLOAD1(v1b[1][1], Vp1);
    Kp += 1024; Vp0 += 1024; Vp1 += 1024;

    f32x16 ofA0 = {}, ofA1 = {}, ofB0 = {}, ofB1 = {};
    float mrowA = -INFINITY, lrowA = 0.f;
    float mrowB = -INFINITY, lrowB = 0.f;

    auto compute = [&](int cur) {
        const bf16x8 ck0 = __builtin_bit_cast(bf16x8, kb[cur][0]);
        const bf16x8 ck1 = __builtin_bit_cast(bf16x8, kb[cur][1]);
        const bf16x8 cv0 = __builtin_bit_cast(bf16x8, v0b[cur][0]);
        const bf16x8 cv1 = __builtin_bit_cast(bf16x8, v0b[cur][1]);
        const bf16x8 cv2 = __builtin_bit_cast(bf16x8, v1b[cur][0]);
        const bf16x8 cv3 = __builtin_bit_cast(bf16x8, v1b[cur][1]);
        const bf16x8 qA0 = __builtin_bit_cast(bf16x8, qr0);
        const bf16x8 qA1 = __builtin_bit_cast(bf16x8, qr1);
        const bf16x8 qB0 = __builtin_bit_cast(bf16x8, qr2);
        const bf16x8 qB1 = __builtin_bit_cast(bf16x8, qr3);

        const f32x16 z16 = {};
        f32x16 sa = __builtin_amdgcn_mfma_f32_32x32x16_bf16(ck0, qA0, z16, 0, 0, 0);
        f32x16 sb = __builtin_amdgcn_mfma_f32_32x32x16_bf16(ck0, qB0, z16, 0, 0, 0);
        sa = __builtin_amdgcn_mfma_f32_32x32x16_bf16(ck1, qA1, sa, 0, 0, 0);
        sb = __builtin_amdgcn_mfma_f32_32x32x16_bf16(ck1, qB1, sb, 0, 0, 0);

        float a0 = fmaxf(fmaxf(sa[0], sa[1]), fmaxf(sa[2], sa[3]));
        float a1 = fmaxf(fmaxf(sa[4], sa[5]), fmaxf(sa[6], sa[7]));
        float a2 = fmaxf(fmaxf(sa[8], sa[9]), fmaxf(sa[10], sa[11]));
        float a3 = fmaxf(fmaxf(sa[12], sa[13]), fmaxf(sa[14], sa[15]));
        float mxA = fmaxf(fmaxf(a0, a1), fmaxf(a2, a3));
        float b0 = fmaxf(fmaxf(sb[0], sb[1]), fmaxf(sb[2], sb[3]));
        float b1 = fmaxf(fmaxf(sb[4], sb[5]), fmaxf(sb[6], sb[7]));
        float b2 = fmaxf(fmaxf(sb[8], sb[9]), fmaxf(sb[10], sb[11]));
        float b3 = fmaxf(fmaxf(sb[12], sb[13]), fmaxf(sb[14], sb[15]));
        float mxB = fmaxf(fmaxf(b0, b1), fmaxf(b2, b3));
        mxA = xhalf_max(mxA);      // VALU-rate cross-half max (no LDS)
        mxB = xhalf_max(mxB);

        if (__any(mxA > mrowA + 11.5f)) {
            const float mnew = fmaxf(mrowA, mxA);
            const float fsc = __builtin_amdgcn_exp2f(mrowA - mnew);
            mrowA = mnew; lrowA *= fsc;
            ofA0 *= fsc; ofA1 *= fsc;
        }
        if (__any(mxB > mrowB + 11.5f)) {
            const float mnew = fmaxf(mrowB, mxB);
            const float fsc = __builtin_amdgcn_exp2f(mrowB - mnew);
            mrowB = mnew; lrowB *= fsc;
            ofB0 *= fsc; ofB1 *= fsc;
        }

        float pA[16], pB[16];
        #pragma unroll
        for (int r = 0; r < 16; ++r) pA[r] = __builtin_amdgcn_exp2f(sa[r] - mrowA);
        #pragma unroll
        for (int r = 0; r < 16; ++r) pB[r] = __builtin_amdgcn_exp2f(sb[r] - mrowB);
        lrowA += (((pA[0]+pA[1])+(pA[2]+pA[3])) + ((pA[4]+pA[5])+(pA[6]+pA[7])))
               + (((pA[8]+pA[9])+(pA[10]+pA[11])) + ((pA[12]+pA[13])+(pA[14]+pA[15])));
        lrowB += (((pB[0]+pB[1])+(pB[2]+pB[3])) + ((pB[4]+pB[5])+(pB[6]+pB[7])))
               + (((pB[8]+pB[9])+(pB[10]+pB[11])) + ((pB[12]+pB[13])+(pB[14]+pB[15])));

        u32x4 wA0, wA1, wB0, wB1;
        wA0.x = pack_bf2_trunc(pA[0],  pA[1]);  wA0.y = pack_bf2_trunc(pA[2],  pA[3]);
        wA0.z = pack_bf2_trunc(pA[4],  pA[5]);  wA0.w = pack_bf2_trunc(pA[6],  pA[7]);
        wA1.x = pack_bf2_trunc(pA[8],  pA[9]);  wA1.y = pack_bf2_trunc(pA[10], pA[11]);
        wA1.z = pack_bf2_trunc(pA[12], pA[13]); wA1.w = pack_bf2_trunc(pA[14], pA[15]);
        wB0.x = pack_bf2_trunc(pB[0],  pB[1]);  wB0.y = pack_bf2_trunc(pB[2],  pB[3]);
        wB0.z = pack_bf2_trunc(pB[4],  pB[5]);  wB0.w = pack_bf2_trunc(pB[6],  pB[7]);
        wB1.x = pack_bf2_trunc(pB[8],  pB[9]);  wB1.y = pack_bf2_trunc(pB[10], pB[11]);
        wB1.z = pack_bf2_trunc(pB[12], pB[13]); wB1.w = pack_bf2_trunc(pB[14], pB[15]);
        const bf16x8 pfA0 = __builtin_bit_cast(bf16x8, wA0);
        const bf16x8 pfA1 = __builtin_bit_cast(bf16x8, wA1);
        const bf16x8 pfB0 = __builtin_bit_cast(bf16x8, wB0);
        const bf16x8 pfB1 = __builtin_bit_cast(bf16x8, wB1);

        ofA0 = __builtin_amdgcn_mfma_f32_32x32x16_bf16(cv0, pfA0, ofA0, 0, 0, 0);
        ofB0 = __builtin_amdgcn_mfma_f32_32x32x16_bf16(cv0, pfB0, ofB0, 0, 0, 0);
        ofA0 = __builtin_amdgcn_mfma_f32_32x32x16_bf16(cv1, pfA1, ofA0, 0, 0, 0);
        ofB0 = __builtin_amdgcn_mfma_f32_32x32x16_bf16(cv1, pfB1, ofB0, 0, 0, 0);
        ofA1 = __builtin_amdgcn_mfma_f32_32x32x16_bf16(cv2, pfA0, ofA1, 0, 0, 0);
        ofB1 = __builtin_amdgcn_mfma_f32_32x32x16_bf16(cv2, pfB0, ofB1, 0, 0, 0);
        ofA1 = __builtin_amdgcn_mfma_f32_32x32x16_bf16(cv3, pfA1, ofA1, 0, 0, 0);
        ofB1 = __builtin_amdgcn_mfma_f32_32x32x16_bf16(cv3, pfB1, ofB1, 0, 0, 0);
    };

    auto issue = [&](int cur) {
        GLOAD0(kb[cur][0], Kp);  GLOAD1(kb[cur][1], Kp);
        GLOAD0(v0b[cur][0], Vp0); GLOAD1(v0b[cur][1], Vp0);
        GLOAD0(v1b[cur][0], Vp1); GLOAD1(v1b[cur][1], Vp1);
        Kp += 1024; Vp0 += 1024; Vp1 += 1024;
    };

    #pragma unroll 1
    for (int i = 0; i < 7; ++i) {
        WAITV6; SB;
        compute(0); issue(0);
        WAITV6; SB;
        compute(1); issue(1);
    }
    WAITV6; SB;
    compute(0);                       // tile 14
    WAITV0; SB;
    compute(1);                       // tile 15

    // ---- merge kv partials ----
    lrowA += __shfl_xor(lrowA, 32);
    lrowB += __shfl_xor(lrowB, 32);
    if (kv == 1) {
        #pragma unroll
        for (int r = 0; r < 16; ++r) {
            Xof[((ch * 2 + 0) * 16 + r) * 64 + l]        = ofA0[r];
            Xof[((ch * 2 + 1) * 16 + r) * 64 + l]        = ofA1[r];
            Xof[4096 + ((ch * 2 + 0) * 16 + r) * 64 + l] = ofB0[r];
            Xof[4096 + ((ch * 2 + 1) * 16 + r) * 64 + l] = ofB1[r];
        }
        if (h == 0) {
            mlM[ch * 32 + xl] = mrowA;      mlL[ch * 32 + xl] = lrowA;
            mlM[64 + ch * 32 + xl] = mrowB; mlL[64 + ch * 32 + xl] = lrowB;
        }
    }
    __syncthreads();

    if (kv == 0) {
        const float g = gamma[0];
        const int b = bh >> 2, hd = bh & 3;
        const size_t base = ((size_t)b * CH + hd * 128 + ch * 64) * NPIX + n0;
        // group A
        {
            const float mB_ = mlM[ch * 32 + xl], lB_ = mlL[ch * 32 + xl];
            const float ms = fmaxf(mrowA, mB_);
            const float fA = __builtin_amdgcn_exp2f(mrowA - ms);
            const float fB = __builtin_amdgcn_exp2f(mB_ - ms);
            const float inv = 1.0f / (lrowA * fA + lB_ * fB);
            const float sA = fA * inv, sB = fB * inv;
            #pragma unroll
            for (int cb = 0; cb < 2; ++cb)
                #pragma unroll
                for (int r = 0; r < 16; ++r) {
                    const float own = cb ? ofA1[r] : ofA0[r];
                    const float dn  = Xof[((ch * 2 + cb) * 16 + r) * 64 + l];
                    const int   c   = cb * 32 + (r & 3) + 8 * (r >> 2) + 4 * h;
                    const size_t gi = base + (size_t)c * NPIX + xl;
                    out[gi] = fmaf(g, own * sA + dn * sB, x[gi]);
                }
        }
        // group B (rows n0+32..n0+63)
        {
            const float mB_ = mlM[64 + ch * 32 + xl], lB_ = mlL[64 + ch * 32 + xl];
            const float ms = fmaxf(mrowB, mB_);
            const float fA = __builtin_amdgcn_exp2f(mrowB - ms);
            const float fB = __builtin_amdgcn_exp2f(mB_ - ms);
            const float inv = 1.0f / (lrowB * fA + lB_ * fB);
            const float sA = fA * inv, sB = fB * inv;
            #pragma unroll
            for (int cb = 0; cb < 2; ++cb)
                #pragma unroll
                for (int r = 0; r < 16; ++r) {
                    const float own = cb ? ofB1[r] : ofB0[r];
                    const float dn  = Xof[4096 + ((ch * 2 + cb) * 16 + r) * 64 + l];
                    const int   c   = cb * 32 + (r & 3) + 8 * (r >> 2) + 4 * h;
                    const size_t gi = base + (size_t)c * NPIX + 32 + xl;
                    out[gi] = fmaf(g, own * sA + dn * sB, x[gi]);
                }
        }
    }
}

// ---------------------------------------------------------------------------
extern "C" void kernel_launch(void* const* d_in, const int* in_sizes, int n_in,
                              void* d_out, int out_size, void* d_ws, size_t ws_size,
                              hipStream_t stream)
{
    const float* x     = (const float*)d_in[0];
    const float* Wq    = (const float*)d_in[1];
    const float* bq    = (const float*)d_in[2];
    const float* Wk    = (const float*)d_in[3];
    const float* bk    = (const float*)d_in[4];
    const float* Wv    = (const float*)d_in[5];
    const float* bv    = (const float*)d_in[6];
    const float* gamma = (const float*)d_in[7];
    float* out = (float*)d_out;

    char* ws = (char*)d_ws;
    unsigned short* XTFp = (unsigned short*)(ws);             // 8 MB
    unsigned short* WFp  = (unsigned short*)(ws + 8388608);   // 768 KB
    unsigned short* QFp  = (unsigned short*)(ws + 9175040);   // 2 MB
    unsigned short* KFp  = (unsigned short*)(ws + 11272192);  // 2 MB
    unsigned short* VFp  = (unsigned short*)(ws + 13369344);  // 8 MB

    prep<<<dim3(16, 8, 9), 256, 0, stream>>>(x, Wq, Wk, Wv, XTFp, WFp);
    qkv_proj<<<dim3(8, 12, 8), 256, 0, stream>>>(XTFp, WFp, bq, bk, bv, QFp, KFp, VFp);
    attn<<<dim3(512), 256, 0, stream>>>(QFp, KFp, VFp, x, gamma, out);
}